// Round 5
// baseline (4787.283 us; speedup 1.0000x reference)
//
#include <hip/hip_runtime.h>

typedef unsigned short USH;
typedef __attribute__((ext_vector_type(8))) short bf16x8;   // 8 bf16 = 4 VGPR
typedef __attribute__((ext_vector_type(4))) float f32x4;

#define MFMA16(a,b,c) __builtin_amdgcn_mfma_f32_16x16x32_bf16((a),(b),(c),0,0,0)

#define BB 4
#define HH 192
#define NN 36864            // 192*192
#define NTOT 147456         // 4*NN

__device__ __forceinline__ float bf2f(USH h) {
    union { unsigned int u; float f; } v; v.u = ((unsigned int)h) << 16; return v.f;
}
__device__ __forceinline__ USH f2bf(float f) {
    union { float f; unsigned int u; } v; v.f = f;
    unsigned int u = v.u;
    return (USH)((u + 0x7FFFu + ((u >> 16) & 1u)) >> 16);
}

// ---------------------------------------------------------------- transpose x: fp32 [b][c][n] -> bf16 [b][n][c]
__global__ void transpose64_k(const float* __restrict__ in, USH* __restrict__ out) {
    __shared__ float tf[64][65];
    int bid = blockIdx.x; int b = bid / 576; int nt = bid - b * 576; int n0 = nt * 64;
    int tid = threadIdx.x;
    for (int p = 0; p < 16; ++p) {
        int idx = p * 256 + tid; int c = idx >> 6, nn = idx & 63;
        tf[nn][c] = in[((size_t)b * 64 + c) * NN + n0 + nn];
    }
    __syncthreads();
    for (int p = 0; p < 16; ++p) {
        int idx = p * 256 + tid; int nn = idx >> 6, c = idx & 63;
        out[((size_t)b * NN + n0 + nn) * 64 + c] = f2bf(tf[nn][c]);
    }
}

// ---------------------------------------------------------------- prep QKV A-frags + bias (fp32 weights in)
__global__ void prep_qkv_k(const float* __restrict__ wq, const float* __restrict__ wk, const float* __restrict__ wv,
                           const float* __restrict__ qg, const float* __restrict__ qb,
                           const float* __restrict__ vg, const float* __restrict__ vb,
                           USH* __restrict__ apre, float* __restrict__ bias) {
    int t = blockIdx.x * 256 + threadIdx.x;
    if (t < 1536) {
        int lane = t & 63, chunk = t >> 6;
        int mt = chunk >> 1, kc = chunk & 1;
        int o = mt * 16 + (lane & 15);
        int c0 = kc * 32 + (lane >> 4) * 8;
        float scale; const float* wrow;
        if (o < 64)       { scale = qg[o]       * rsqrtf(1.0f + 1e-5f); wrow = wq + o * 64; }
        else if (o < 128) { scale = 1.0f;                               wrow = wk + (o - 64) * 64; }
        else              { scale = vg[o - 128] * rsqrtf(1.0f + 1e-5f); wrow = wv + (o - 128) * 64; }
        for (int j = 0; j < 8; ++j) apre[t * 8 + j] = f2bf(wrow[c0 + j] * scale);
    }
    if (t < 192) {
        float bvv;
        if (t < 64) bvv = qb[t]; else if (t < 128) bvv = 0.0f; else bvv = vb[t - 128];
        bias[t] = bvv;
    }
}

// ---------------------------------------------------------------- prep conv A-frags (8 shifts x 4 u x 23 dy)
// chunk cg = (r*4+u)*23+dy ; value slot k=(lane>>4)*8+j -> dx=k-r ; kk = lane&15
__global__ void prep_conv_k(const float* __restrict__ pw, USH* __restrict__ apre) {
    int t = blockIdx.x * 256 + threadIdx.x;
    if (t >= 736 * 64) return;
    int lane = t & 63, cg = t >> 6;
    int dy = cg % 23; int ru = cg / 23; int u = ru & 3; int r = ru >> 2;
    int kk = lane & 15, q8 = (lane >> 4) * 8;
    for (int j = 0; j < 8; ++j) {
        int k = q8 + j, dx = k - r;
        USH w = 0;
        if (dx >= 0 && dx < 23) w = f2bf(pw[((kk * 4 + u) * 23 + dy) * 23 + dx]);
        apre[t * 8 + j] = w;
    }
}

// ---------------------------------------------------------------- prep final A-frags (cw 64x64, fp32 in)
__global__ void prep_fin_k(const float* __restrict__ cw, USH* __restrict__ apre) {
    int t = blockIdx.x * 256 + threadIdx.x;
    if (t >= 8 * 64) return;
    int lane = t & 63, chunk = t >> 6;
    int mt = chunk >> 1, kc = chunk & 1;
    int o = mt * 16 + (lane & 15);
    int c0 = kc * 32 + (lane >> 4) * 8;
    for (int j = 0; j < 8; ++j) apre[t * 8 + j] = f2bf(cw[o * 64 + c0 + j]);
}

// ---------------------------------------------------------------- QKV GEMM (MFMA, B from global XT)
__global__ __launch_bounds__(256) void qkv_gemm_k(
    const USH* __restrict__ XT, const bf16x8* __restrict__ apre, const float* __restrict__ bias,
    USH* __restrict__ qT, USH* __restrict__ kbuf, USH* __restrict__ vbuf) {
    const int tid = threadIdx.x, lane = tid & 63, wv = tid >> 6;
    const int gw = blockIdx.x * 4 + wv;
    const int nl = lane & 15, quad = lane >> 4;
    bf16x8 afr[24];
    #pragma unroll
    for (int i = 0; i < 24; ++i) afr[i] = apre[i * 64 + lane];
    for (int t = 0; t < 16; ++t) {
        int tile = gw * 16 + t;
        int b = tile / 2304, nt = tile - b * 2304;
        int n = nt * 16 + nl;
        const USH* xrow = XT + ((size_t)b * NN + n) * 64 + quad * 8;
        bf16x8 b0 = *(const bf16x8*)(xrow);
        bf16x8 b1 = *(const bf16x8*)(xrow + 32);
        #pragma unroll
        for (int mt = 0; mt < 12; ++mt) {
            f32x4 acc = {0.f, 0.f, 0.f, 0.f};
            acc = MFMA16(afr[mt * 2 + 0], b0, acc);
            acc = MFMA16(afr[mt * 2 + 1], b1, acc);
            int o0 = mt * 16 + quad * 4;
            float4 bs = *(const float4*)(bias + o0);
            float v0 = acc[0] + bs.x, v1 = acc[1] + bs.y, v2 = acc[2] + bs.z, v3 = acc[3] + bs.w;
            if (mt < 4) {                       // q -> qT[b][n][o] (o = h*16+kk)
                ushort4 pk; pk.x = f2bf(v0); pk.y = f2bf(v1); pk.z = f2bf(v2); pk.w = f2bf(v3);
                *(ushort4*)(qT + ((size_t)b * NN + n) * 64 + o0) = pk;
            } else if (mt < 8) {                // k raw -> kbuf[b][u*16+kk][n]
                int ko = o0 - 64;
                kbuf[((size_t)b * 64 + ko    ) * NN + n] = f2bf(v0);
                kbuf[((size_t)b * 64 + ko + 1) * NN + n] = f2bf(v1);
                kbuf[((size_t)b * 64 + ko + 2) * NN + n] = f2bf(v2);
                kbuf[((size_t)b * 64 + ko + 3) * NN + n] = f2bf(v3);
            } else {                            // v -> vbuf[(b*16+vv)*4+u][n]
                int u = mt - 8, vv0 = quad * 4;
                vbuf[(((size_t)b * 16 + vv0    ) * 4 + u) * NN + n] = f2bf(v0);
                vbuf[(((size_t)b * 16 + vv0 + 1) * 4 + u) * NN + n] = f2bf(v1);
                vbuf[(((size_t)b * 16 + vv0 + 2) * 4 + u) * NN + n] = f2bf(v2);
                vbuf[(((size_t)b * 16 + vv0 + 3) * 4 + u) * NN + n] = f2bf(v3);
            }
        }
    }
}

// ---------------------------------------------------------------- softmax over n, in-place, 1 block/row
__global__ void softmax_k(USH* __restrict__ kbuf) {
    USH* p = kbuf + (size_t)blockIdx.x * NN;
    __shared__ float red[64];
    int tid = threadIdx.x, lane = tid & 63, w = tid >> 6;
    float m = -1e30f;
    for (int i = tid; i < NN; i += 1024) m = fmaxf(m, bf2f(p[i]));
    for (int off = 32; off; off >>= 1) m = fmaxf(m, __shfl_down(m, off));
    if (lane == 0) red[w] = m;
    __syncthreads();
    if (tid == 0) { float mm = red[0]; for (int i = 1; i < 16; ++i) mm = fmaxf(mm, red[i]); red[16] = mm; }
    __syncthreads();
    float M = red[16];
    float s = 0.f;
    for (int i = tid; i < NN; i += 1024) s += __expf(bf2f(p[i]) - M);
    for (int off = 32; off; off >>= 1) s += __shfl_down(s, off);
    if (lane == 0) red[32 + w] = s;
    __syncthreads();
    if (tid == 0) { float ss = 0.f; for (int i = 0; i < 16; ++i) ss += red[32 + i]; red[17] = 1.0f / ss; }
    __syncthreads();
    float inv = red[17];
    for (int i = tid; i < NN; i += 1024) p[i] = f2bf(__expf(bf2f(p[i]) - M) * inv);
}

// ---------------------------------------------------------------- lam_c split-K
__global__ void lamc_stage1_k(const USH* __restrict__ kbuf, const USH* __restrict__ vbuf,
                              float* __restrict__ part) {
    int bid = blockIdx.x;                  // (cidx 0..35)*16 + b*4 + u
    int cidx = bid / 16; int rem = bid - cidx * 16; int b = rem >> 2; int u = rem & 3;
    int tid = threadIdx.x; int vv = tid >> 4; int kk = tid & 15;
    const USH* kp = kbuf + ((size_t)b * 64 + u * 16 + kk) * NN + cidx * 1024;
    const USH* vp = vbuf + (((size_t)b * 16 + vv) * 4 + u) * NN + cidx * 1024;
    float acc = 0.f;
    for (int i = 0; i < 1024; i += 4) {
        ushort4 k4 = *(const ushort4*)(kp + i);
        ushort4 v4 = *(const ushort4*)(vp + i);
        acc += bf2f(k4.x) * bf2f(v4.x) + bf2f(k4.y) * bf2f(v4.y)
             + bf2f(k4.z) * bf2f(v4.z) + bf2f(k4.w) * bf2f(v4.w);
    }
    part[((size_t)(cidx * 4 + b) * 4 + u) * 256 + tid] = acc;
}
__global__ void lamc_stage2_k(const float* __restrict__ part, const float* __restrict__ pb,
                              float* __restrict__ lamcf) {
    int b = blockIdx.x, tid = threadIdx.x;   // tid = vv*16+kk
    float acc = 0.f;
    for (int c = 0; c < 36; ++c)
        for (int u = 0; u < 4; ++u)
            acc += part[((size_t)(c * 4 + b) * 4 + u) * 256 + tid];
    lamcf[b * 256 + tid] = acc + pb[tid & 15];   // fold conv bias pb[kk]
}

// ---------------------------------------------------------------- position conv 23x23 (MFMA implicit GEMM)
// + FUSED y-epilogue. 2-way r-BLOCKED: each B LDS read feeds 2 r-variants
// (acc[2][6] = 48 VGPRs -> no spill; R4's 4-way at 96+ VGPRs spilled to scratch).
// block: (xh 0..1, yt 0..5, img 0..63) covers 32y x 96x for one (b,vv) image.
// wave: wy=y-half(16 rows), wx=x-half(48 cols). MFMA N-dim = 16 y-rows (n=lane&15).
// D-frag: row kk = quad*4+reg, col y = lane&15. shfl_xor(16,32) completes kk-sum.
__global__ __launch_bounds__(256, 2) void conv_pos_fused_k(
    const USH* __restrict__ vbuf, const bf16x8* __restrict__ apre,
    const USH* __restrict__ qT, const float* __restrict__ lamcf,
    USH* __restrict__ yb) {
    __shared__ __align__(16) USH in_s[4 * 54 * 136];      // 58,752 B
    __shared__ float lc_s[16];
    const int xh = blockIdx.x, yt = blockIdx.y, img = blockIdx.z;
    const int b = img >> 4, vvch = img & 15;
    const int tid = threadIdx.x;
    if (tid < 16) lc_s[tid] = lamcf[b * 256 + vvch * 16 + tid];
    {
        const USH* vb = vbuf + (size_t)img * 4 * NN;
        const int y0 = yt * 32 - 11, x0 = xh * 96 - 11;
        for (int idx = tid; idx < 4 * 54 * 136; idx += 256) {
            int u = idx / (54 * 136);
            int rem = idx - u * (54 * 136);
            int rr = rem / 136;
            int cc = rem - rr * 136;
            int gy = y0 + rr, gx = x0 + cc;
            USH val = 0;
            if (gy >= 0 && gy < HH && gx >= 0 && gx < HH) val = vb[u * NN + gy * HH + gx];
            in_s[idx] = val;
        }
    }
    __syncthreads();

    const int lane = tid & 63, wv = tid >> 6;
    const int wy = wv >> 1, wx = wv & 1;
    const int nl = lane & 15, quad = lane >> 4;
    const USH* sbase = in_s + (wy * 16 + nl) * 136 + wx * 48 + quad * 8;
    const int ybase = yt * 32 + wy * 16 + nl;
    float lcr0 = lc_s[quad * 4], lcr1 = lc_s[quad * 4 + 1],
          lcr2 = lc_s[quad * 4 + 2], lcr3 = lc_s[quad * 4 + 3];
    const USH* qbase = qT + ((size_t)b * NN + ybase * HH) * 64 + quad * 4;
    USH* ybbase = yb + ((size_t)b * 64 + quad * 16 + vvch) * NN + ybase * HH;

    for (int rp = 0; rp < 4; ++rp) {
        f32x4 acc[2][6] = {};
        for (int u = 0; u < 4; ++u) {
            const USH* su = sbase + u * (54 * 136);
            const bf16x8* ap0 = apre + ((size_t)((2 * rp) * 4 + u) * 23) * 64 + lane;
            const bf16x8* ap1 = ap0 + 4 * 23 * 64;      // next r
            bf16x8 a0 = ap0[0], a1 = ap1[0];
            for (int dy = 0; dy < 23; ++dy) {
                bf16x8 c0 = a0, c1 = a1;
                if (dy < 22) { a0 = ap0[(dy + 1) * 64]; a1 = ap1[(dy + 1) * 64]; }
                const USH* srow = su + dy * 136;
                #pragma unroll
                for (int xi = 0; xi < 6; ++xi) {
                    bf16x8 bfr = *(const bf16x8*)(srow + 8 * xi);
                    acc[0][xi] = MFMA16(c0, bfr, acc[0][xi]);
                    acc[1][xi] = MFMA16(c1, bfr, acc[1][xi]);
                }
            }
        }
        // fused y-epilogue for this pair's 2 r-variants
        #pragma unroll
        for (int ri = 0; ri < 2; ++ri) {
            int r = rp * 2 + ri;
            #pragma unroll
            for (int xi = 0; xi < 6; ++xi) {
                int x = xh * 96 + wx * 48 + r + 8 * xi;
                float l0 = acc[ri][xi][0] + lcr0, l1 = acc[ri][xi][1] + lcr1;
                float l2 = acc[ri][xi][2] + lcr2, l3 = acc[ri][xi][3] + lcr3;
                const USH* qp = qbase + (size_t)x * 64;
                float s0, s1, s2, s3;
                {
                    ushort4 q4 = *(const ushort4*)(qp);
                    s0 = bf2f(q4.x) * l0 + bf2f(q4.y) * l1 + bf2f(q4.z) * l2 + bf2f(q4.w) * l3;
                }
                {
                    ushort4 q4 = *(const ushort4*)(qp + 16);
                    s1 = bf2f(q4.x) * l0 + bf2f(q4.y) * l1 + bf2f(q4.z) * l2 + bf2f(q4.w) * l3;
                }
                {
                    ushort4 q4 = *(const ushort4*)(qp + 32);
                    s2 = bf2f(q4.x) * l0 + bf2f(q4.y) * l1 + bf2f(q4.z) * l2 + bf2f(q4.w) * l3;
                }
                {
                    ushort4 q4 = *(const ushort4*)(qp + 48);
                    s3 = bf2f(q4.x) * l0 + bf2f(q4.y) * l1 + bf2f(q4.z) * l2 + bf2f(q4.w) * l3;
                }
                s0 += __shfl_xor(s0, 16); s0 += __shfl_xor(s0, 32);
                s1 += __shfl_xor(s1, 16); s1 += __shfl_xor(s1, 32);
                s2 += __shfl_xor(s2, 16); s2 += __shfl_xor(s2, 32);
                s3 += __shfl_xor(s3, 16); s3 += __shfl_xor(s3, 32);
                float sel = (quad == 0) ? s0 : (quad == 1) ? s1 : (quad == 2) ? s2 : s3;
                ybbase[x] = f2bf(sel);
            }
        }
    }
}

// ---------------------------------------------------------------- GroupNorm
__global__ void gn_passA_k(const USH* __restrict__ yb, float* __restrict__ part) {
    int bid = blockIdx.x;                  // (b*8+g)*18 + cz
    int cz = bid % 18; int bg = bid / 18;
    int tid = threadIdx.x;
    const USH* base = yb + (size_t)bg * 8 * NN + cz * 2048;
    float s = 0.f, sq = 0.f;
    for (int c = 0; c < 8; ++c) {
        const USH* p = base + (size_t)c * NN;
        for (int i = tid * 4; i < 2048; i += 1024) {
            ushort4 t4 = *(const ushort4*)(p + i);
            float f0 = bf2f(t4.x), f1 = bf2f(t4.y), f2 = bf2f(t4.z), f3 = bf2f(t4.w);
            s += f0 + f1 + f2 + f3;
            sq += f0 * f0 + f1 * f1 + f2 * f2 + f3 * f3;
        }
    }
    for (int off = 32; off; off >>= 1) { s += __shfl_down(s, off); sq += __shfl_down(sq, off); }
    __shared__ float rs[4], rq[4];
    int w = tid >> 6, lane = tid & 63;
    if (lane == 0) { rs[w] = s; rq[w] = sq; }
    __syncthreads();
    if (tid == 0) {
        part[bid * 2]     = rs[0] + rs[1] + rs[2] + rs[3];
        part[bid * 2 + 1] = rq[0] + rq[1] + rq[2] + rq[3];
    }
}
__global__ void gn_passB_k(const float* __restrict__ part, float* __restrict__ stats) {
    int t = threadIdx.x;
    if (t < 32) {
        float s = 0.f, q = 0.f;
        for (int c = 0; c < 18; ++c) { s += part[(t * 18 + c) * 2]; q += part[(t * 18 + c) * 2 + 1]; }
        float mean = s / 294912.0f;
        float var = q / 294912.0f - mean * mean;
        stats[t * 2] = mean;
        stats[t * 2 + 1] = rsqrtf(fmaxf(var, 0.0f) + 1e-5f);
    }
}
// normalize + affine + transpose to XT[b][n][c]  (gamma/beta fp32)
__global__ void gn_passC_k(const USH* __restrict__ yb, const float* __restrict__ stats,
                           const float* __restrict__ gg, const float* __restrict__ gb,
                           USH* __restrict__ out) {
    __shared__ float tf[64][65];
    __shared__ float sc[64], sb[64];
    int bid = blockIdx.x; int b = bid / 576; int nt = bid - b * 576; int n0 = nt * 64;
    int tid = threadIdx.x;
    if (tid < 64) {
        int g = tid >> 3;
        float mean = stats[(b * 8 + g) * 2], rstd = stats[(b * 8 + g) * 2 + 1];
        float ga = gg[tid];
        sc[tid] = rstd * ga;
        sb[tid] = gb[tid] - mean * rstd * ga;
    }
    __syncthreads();
    for (int p = 0; p < 16; ++p) {
        int idx = p * 256 + tid; int c = idx >> 6, nn = idx & 63;
        tf[nn][c] = bf2f(yb[((size_t)b * 64 + c) * NN + n0 + nn]) * sc[c] + sb[c];
    }
    __syncthreads();
    for (int p = 0; p < 16; ++p) {
        int idx = p * 256 + tid; int nn = idx >> 6, c = idx & 63;
        out[((size_t)b * NN + n0 + nn) * 64 + c] = f2bf(tf[nn][c]);
    }
}

// ---------------------------------------------------------------- final conv1x1 + *0.2 + x (fp32 out)
__global__ __launch_bounds__(256) void final_gemm_k(
    const USH* __restrict__ XT, const bf16x8* __restrict__ apre,
    const float* __restrict__ cb, const float* __restrict__ xin, float* __restrict__ out) {
    const int tid = threadIdx.x, lane = tid & 63, wv = tid >> 6;
    const int gw = blockIdx.x * 4 + wv;
    const int nl = lane & 15, quad = lane >> 4;
    bf16x8 afr[8];
    #pragma unroll
    for (int i = 0; i < 8; ++i) afr[i] = apre[i * 64 + lane];
    for (int t = 0; t < 16; ++t) {
        int tile = gw * 16 + t;
        int b = tile / 2304, nt = tile - b * 2304;
        int n = nt * 16 + nl;
        const USH* xrow = XT + ((size_t)b * NN + n) * 64 + quad * 8;
        bf16x8 b0 = *(const bf16x8*)(xrow);
        bf16x8 b1 = *(const bf16x8*)(xrow + 32);
        #pragma unroll
        for (int mt = 0; mt < 4; ++mt) {
            f32x4 acc = {0.f, 0.f, 0.f, 0.f};
            acc = MFMA16(afr[mt * 2 + 0], b0, acc);
            acc = MFMA16(afr[mt * 2 + 1], b1, acc);
            int o0 = mt * 16 + quad * 4;
            float4 cb4 = *(const float4*)(cb + o0);
            float cbv[4] = { cb4.x, cb4.y, cb4.z, cb4.w };
            #pragma unroll
            for (int rg = 0; rg < 4; ++rg) {
                int o = o0 + rg;
                float xv = xin[((size_t)b * 64 + o) * NN + n];
                out[((size_t)b * 64 + o) * NN + n] = (acc[rg] + cbv[rg]) * 0.2f + xv;
            }
        }
    }
}

// ================================================================ host
extern "C" void kernel_launch(void* const* d_in, const int* in_sizes, int n_in,
                              void* d_out, int out_size, void* d_ws, size_t ws_size,
                              hipStream_t stream) {
    (void)in_sizes; (void)n_in; (void)out_size; (void)ws_size;
    const float* x = (const float*)d_in[0];
    char* ws = (char*)d_ws;

    // Workspace layout: 4 big bf16 planes + small tail = ~73.3 MiB total.
    // ybuf aliases kbuf (kbuf is dead after lamc_stage1).
    const size_t SZP = (size_t)NTOT * 64 * 2;          // 18,874,368 B
    USH*   XT    = (USH*)(ws);
    USH*   qT    = (USH*)(ws + SZP);
    USH*   kbuf  = (USH*)(ws + 2 * SZP);
    USH*   ybuf  = kbuf;                               // alias
    USH*   vbuf  = (USH*)(ws + 3 * SZP);
    char*  tail  = ws + 4 * SZP;
    USH*   apc   = (USH*)(tail);            tail += 753664;   // conv A-frags
    USH*   apq   = (USH*)(tail);            tail += 24576;    // qkv A-frags
    float* biasq = (float*)(tail);          tail += 768;
    USH*   apf   = (USH*)(tail);            tail += 8192;     // final A-frags
    float* lcp   = (float*)(tail);          tail += 589824;   // lam_c partials
    float* lcf   = (float*)(tail);          tail += 4096;     // lam_c + pb, [b][vv][kk]
    float* gnp   = (float*)(tail);          tail += 4608;     // GN partials
    float* gns   = (float*)(tail);                            // GN mean/rstd (256 B)

    transpose64_k<<<2304, 256, 0, stream>>>(x, XT);

    for (int L = 0; L < 3; ++L) {
        int base = 1 + L * 9;
        const float* wq = (const float*)d_in[base + 0];
        const float* wk = (const float*)d_in[base + 1];
        const float* wv = (const float*)d_in[base + 2];
        const float* qg = (const float*)d_in[base + 3];
        const float* qb = (const float*)d_in[base + 4];
        const float* vg = (const float*)d_in[base + 5];
        const float* vb = (const float*)d_in[base + 6];
        const float* pw = (const float*)d_in[base + 7];
        const float* pb = (const float*)d_in[base + 8];

        prep_qkv_k<<<6, 256, 0, stream>>>(wq, wk, wv, qg, qb, vg, vb, apq, biasq);
        prep_conv_k<<<184, 256, 0, stream>>>(pw, apc);
        qkv_gemm_k<<<144, 256, 0, stream>>>(XT, (const bf16x8*)apq, biasq, qT, kbuf, vbuf);
        softmax_k<<<256, 1024, 0, stream>>>(kbuf);
        lamc_stage1_k<<<576, 256, 0, stream>>>(kbuf, vbuf, lcp);
        lamc_stage2_k<<<4, 256, 0, stream>>>(lcp, pb, lcf);
        dim3 cg(2, 6, 64);
        conv_pos_fused_k<<<cg, 256, 0, stream>>>(vbuf, (const bf16x8*)apc, qT, lcf, ybuf);
        gn_passA_k<<<576, 256, 0, stream>>>(ybuf, gnp);
        gn_passB_k<<<1, 256, 0, stream>>>(gnp, gns);
        const float* gg = (const float*)d_in[(L == 2) ? 30 : 28];
        const float* gb = (const float*)d_in[(L == 2) ? 31 : 29];
        gn_passC_k<<<2304, 256, 0, stream>>>(ybuf, gns, gg, gb, XT);
    }

    prep_fin_k<<<2, 256, 0, stream>>>((const float*)d_in[32], apf);
    final_gemm_k<<<144, 256, 0, stream>>>(XT, (const bf16x8*)apf,
                                          (const float*)d_in[33], x, (float*)d_out);
}

// Round 6
// 1598.800 us; speedup vs baseline: 2.9943x; 2.9943x over previous
//
#include <hip/hip_runtime.h>

typedef unsigned short USH;
typedef __attribute__((ext_vector_type(8))) short bf16x8;   // 8 bf16 = 4 VGPR
typedef __attribute__((ext_vector_type(4))) float f32x4;

#define MFMA16(a,b,c) __builtin_amdgcn_mfma_f32_16x16x32_bf16((a),(b),(c),0,0,0)

#define BB 4
#define HH 192
#define NN 36864            // 192*192
#define NTOT 147456         // 4*NN

__device__ __forceinline__ float bf2f(USH h) {
    union { unsigned int u; float f; } v; v.u = ((unsigned int)h) << 16; return v.f;
}
__device__ __forceinline__ USH f2bf(float f) {
    union { float f; unsigned int u; } v; v.f = f;
    unsigned int u = v.u;
    return (USH)((u + 0x7FFFu + ((u >> 16) & 1u)) >> 16);
}

// ---------------------------------------------------------------- transpose x: fp32 [b][c][n] -> bf16 [b][n][c]
__global__ void transpose64_k(const float* __restrict__ in, USH* __restrict__ out) {
    __shared__ float tf[64][65];
    int bid = blockIdx.x; int b = bid / 576; int nt = bid - b * 576; int n0 = nt * 64;
    int tid = threadIdx.x;
    for (int p = 0; p < 16; ++p) {
        int idx = p * 256 + tid; int c = idx >> 6, nn = idx & 63;
        tf[nn][c] = in[((size_t)b * 64 + c) * NN + n0 + nn];
    }
    __syncthreads();
    for (int p = 0; p < 16; ++p) {
        int idx = p * 256 + tid; int nn = idx >> 6, c = idx & 63;
        out[((size_t)b * NN + n0 + nn) * 64 + c] = f2bf(tf[nn][c]);
    }
}

// ---------------------------------------------------------------- prep QKV A-frags + bias (fp32 weights in)
__global__ void prep_qkv_k(const float* __restrict__ wq, const float* __restrict__ wk, const float* __restrict__ wv,
                           const float* __restrict__ qg, const float* __restrict__ qb,
                           const float* __restrict__ vg, const float* __restrict__ vb,
                           USH* __restrict__ apre, float* __restrict__ bias) {
    int t = blockIdx.x * 256 + threadIdx.x;
    if (t < 1536) {
        int lane = t & 63, chunk = t >> 6;
        int mt = chunk >> 1, kc = chunk & 1;
        int o = mt * 16 + (lane & 15);
        int c0 = kc * 32 + (lane >> 4) * 8;
        float scale; const float* wrow;
        if (o < 64)       { scale = qg[o]       * rsqrtf(1.0f + 1e-5f); wrow = wq + o * 64; }
        else if (o < 128) { scale = 1.0f;                               wrow = wk + (o - 64) * 64; }
        else              { scale = vg[o - 128] * rsqrtf(1.0f + 1e-5f); wrow = wv + (o - 128) * 64; }
        for (int j = 0; j < 8; ++j) apre[t * 8 + j] = f2bf(wrow[c0 + j] * scale);
    }
    if (t < 192) {
        float bvv;
        if (t < 64) bvv = qb[t]; else if (t < 128) bvv = 0.0f; else bvv = vb[t - 128];
        bias[t] = bvv;
    }
}

// ---------------------------------------------------------------- prep conv A-frags (8 shifts x 4 u x 23 dy)
// chunk cg = (r*4+u)*23+dy ; value slot k=(lane>>4)*8+j -> dx=k-r ; kk = lane&15
__global__ void prep_conv_k(const float* __restrict__ pw, USH* __restrict__ apre) {
    int t = blockIdx.x * 256 + threadIdx.x;
    if (t >= 736 * 64) return;
    int lane = t & 63, cg = t >> 6;
    int dy = cg % 23; int ru = cg / 23; int u = ru & 3; int r = ru >> 2;
    int kk = lane & 15, q8 = (lane >> 4) * 8;
    for (int j = 0; j < 8; ++j) {
        int k = q8 + j, dx = k - r;
        USH w = 0;
        if (dx >= 0 && dx < 23) w = f2bf(pw[((kk * 4 + u) * 23 + dy) * 23 + dx]);
        apre[t * 8 + j] = w;
    }
}

// ---------------------------------------------------------------- prep final A-frags (cw 64x64, fp32 in)
__global__ void prep_fin_k(const float* __restrict__ cw, USH* __restrict__ apre) {
    int t = blockIdx.x * 256 + threadIdx.x;
    if (t >= 8 * 64) return;
    int lane = t & 63, chunk = t >> 6;
    int mt = chunk >> 1, kc = chunk & 1;
    int o = mt * 16 + (lane & 15);
    int c0 = kc * 32 + (lane >> 4) * 8;
    for (int j = 0; j < 8; ++j) apre[t * 8 + j] = f2bf(cw[o * 64 + c0 + j]);
}

// ---------------------------------------------------------------- QKV GEMM (MFMA, B from global XT)
__global__ __launch_bounds__(256) void qkv_gemm_k(
    const USH* __restrict__ XT, const bf16x8* __restrict__ apre, const float* __restrict__ bias,
    USH* __restrict__ qT, USH* __restrict__ kbuf, USH* __restrict__ vbuf) {
    const int tid = threadIdx.x, lane = tid & 63, wv = tid >> 6;
    const int gw = blockIdx.x * 4 + wv;
    const int nl = lane & 15, quad = lane >> 4;
    bf16x8 afr[24];
    #pragma unroll
    for (int i = 0; i < 24; ++i) afr[i] = apre[i * 64 + lane];
    for (int t = 0; t < 16; ++t) {
        int tile = gw * 16 + t;
        int b = tile / 2304, nt = tile - b * 2304;
        int n = nt * 16 + nl;
        const USH* xrow = XT + ((size_t)b * NN + n) * 64 + quad * 8;
        bf16x8 b0 = *(const bf16x8*)(xrow);
        bf16x8 b1 = *(const bf16x8*)(xrow + 32);
        #pragma unroll
        for (int mt = 0; mt < 12; ++mt) {
            f32x4 acc = {0.f, 0.f, 0.f, 0.f};
            acc = MFMA16(afr[mt * 2 + 0], b0, acc);
            acc = MFMA16(afr[mt * 2 + 1], b1, acc);
            int o0 = mt * 16 + quad * 4;
            float4 bs = *(const float4*)(bias + o0);
            float v0 = acc[0] + bs.x, v1 = acc[1] + bs.y, v2 = acc[2] + bs.z, v3 = acc[3] + bs.w;
            if (mt < 4) {                       // q -> qT[b][n][o] (o = h*16+kk)
                ushort4 pk; pk.x = f2bf(v0); pk.y = f2bf(v1); pk.z = f2bf(v2); pk.w = f2bf(v3);
                *(ushort4*)(qT + ((size_t)b * NN + n) * 64 + o0) = pk;
            } else if (mt < 8) {                // k raw -> kbuf[b][u*16+kk][n]
                int ko = o0 - 64;
                kbuf[((size_t)b * 64 + ko    ) * NN + n] = f2bf(v0);
                kbuf[((size_t)b * 64 + ko + 1) * NN + n] = f2bf(v1);
                kbuf[((size_t)b * 64 + ko + 2) * NN + n] = f2bf(v2);
                kbuf[((size_t)b * 64 + ko + 3) * NN + n] = f2bf(v3);
            } else {                            // v -> vbuf[(b*16+vv)*4+u][n]
                int u = mt - 8, vv0 = quad * 4;
                vbuf[(((size_t)b * 16 + vv0    ) * 4 + u) * NN + n] = f2bf(v0);
                vbuf[(((size_t)b * 16 + vv0 + 1) * 4 + u) * NN + n] = f2bf(v1);
                vbuf[(((size_t)b * 16 + vv0 + 2) * 4 + u) * NN + n] = f2bf(v2);
                vbuf[(((size_t)b * 16 + vv0 + 3) * 4 + u) * NN + n] = f2bf(v3);
            }
        }
    }
}

// ---------------------------------------------------------------- softmax over n, in-place, 1 block/row
__global__ void softmax_k(USH* __restrict__ kbuf) {
    USH* p = kbuf + (size_t)blockIdx.x * NN;
    __shared__ float red[64];
    int tid = threadIdx.x, lane = tid & 63, w = tid >> 6;
    float m = -1e30f;
    for (int i = tid; i < NN; i += 1024) m = fmaxf(m, bf2f(p[i]));
    for (int off = 32; off; off >>= 1) m = fmaxf(m, __shfl_down(m, off));
    if (lane == 0) red[w] = m;
    __syncthreads();
    if (tid == 0) { float mm = red[0]; for (int i = 1; i < 16; ++i) mm = fmaxf(mm, red[i]); red[16] = mm; }
    __syncthreads();
    float M = red[16];
    float s = 0.f;
    for (int i = tid; i < NN; i += 1024) s += __expf(bf2f(p[i]) - M);
    for (int off = 32; off; off >>= 1) s += __shfl_down(s, off);
    if (lane == 0) red[32 + w] = s;
    __syncthreads();
    if (tid == 0) { float ss = 0.f; for (int i = 0; i < 16; ++i) ss += red[32 + i]; red[17] = 1.0f / ss; }
    __syncthreads();
    float inv = red[17];
    for (int i = tid; i < NN; i += 1024) p[i] = f2bf(__expf(bf2f(p[i]) - M) * inv);
}

// ---------------------------------------------------------------- lam_c split-K
__global__ void lamc_stage1_k(const USH* __restrict__ kbuf, const USH* __restrict__ vbuf,
                              float* __restrict__ part) {
    int bid = blockIdx.x;                  // (cidx 0..35)*16 + b*4 + u
    int cidx = bid / 16; int rem = bid - cidx * 16; int b = rem >> 2; int u = rem & 3;
    int tid = threadIdx.x; int vv = tid >> 4; int kk = tid & 15;
    const USH* kp = kbuf + ((size_t)b * 64 + u * 16 + kk) * NN + cidx * 1024;
    const USH* vp = vbuf + (((size_t)b * 16 + vv) * 4 + u) * NN + cidx * 1024;
    float acc = 0.f;
    for (int i = 0; i < 1024; i += 4) {
        ushort4 k4 = *(const ushort4*)(kp + i);
        ushort4 v4 = *(const ushort4*)(vp + i);
        acc += bf2f(k4.x) * bf2f(v4.x) + bf2f(k4.y) * bf2f(v4.y)
             + bf2f(k4.z) * bf2f(v4.z) + bf2f(k4.w) * bf2f(v4.w);
    }
    part[((size_t)(cidx * 4 + b) * 4 + u) * 256 + tid] = acc;
}
__global__ void lamc_stage2_k(const float* __restrict__ part, const float* __restrict__ pb,
                              float* __restrict__ lamcf) {
    int b = blockIdx.x, tid = threadIdx.x;   // tid = vv*16+kk
    float acc = 0.f;
    for (int c = 0; c < 36; ++c)
        for (int u = 0; u < 4; ++u)
            acc += part[((size_t)(c * 4 + b) * 4 + u) * 256 + tid];
    lamcf[b * 256 + tid] = acc + pb[tid & 15];   // fold conv bias pb[kk]
}

// ---------------------------------------------------------------- position conv 23x23 (MFMA implicit GEMM)
// + FUSED y-epilogue. 2-way r-pair per pass, expressed in R3's exact loop shape:
// dy fully unrolled, inline A-loads (no rolling prefetch / no dynamic-index arrays
// -> R4/R5's scratch-spill pathology avoided), two NAMED acc arrays.
// block: (xh 0..1, yt 0..5, img 0..63) covers 32y x 96x for one (b,vv) image.
// D-frag: row kk = quad*4+reg, col y = lane&15. shfl_xor(16,32) completes kk-sum.
__global__ __launch_bounds__(256, 2) void conv_pos_fused_k(
    const USH* __restrict__ vbuf, const bf16x8* __restrict__ apre,
    const USH* __restrict__ qT, const float* __restrict__ lamcf,
    USH* __restrict__ yb) {
    __shared__ __align__(16) USH in_s[4 * 54 * 136];      // 58,752 B
    __shared__ float lc_s[16];
    const int xh = blockIdx.x, yt = blockIdx.y, img = blockIdx.z;
    const int b = img >> 4, vvch = img & 15;
    const int tid = threadIdx.x;
    if (tid < 16) lc_s[tid] = lamcf[b * 256 + vvch * 16 + tid];
    {
        const USH* vb = vbuf + (size_t)img * 4 * NN;
        const int y0 = yt * 32 - 11, x0 = xh * 96 - 11;
        for (int idx = tid; idx < 4 * 54 * 136; idx += 256) {
            int u = idx / (54 * 136);
            int rem = idx - u * (54 * 136);
            int rr = rem / 136;
            int cc = rem - rr * 136;
            int gy = y0 + rr, gx = x0 + cc;
            USH val = 0;
            if (gy >= 0 && gy < HH && gx >= 0 && gx < HH) val = vb[u * NN + gy * HH + gx];
            in_s[idx] = val;
        }
    }
    __syncthreads();

    const int lane = tid & 63, wv = tid >> 6;
    const int wy = wv >> 1, wx = wv & 1;
    const int nl = lane & 15, quad = lane >> 4;
    const USH* sbase = in_s + (wy * 16 + nl) * 136 + wx * 48 + quad * 8;
    const int ybase = yt * 32 + wy * 16 + nl;
    float lcr0 = lc_s[quad * 4], lcr1 = lc_s[quad * 4 + 1],
          lcr2 = lc_s[quad * 4 + 2], lcr3 = lc_s[quad * 4 + 3];
    const USH* qbase = qT + ((size_t)b * NN + ybase * HH) * 64 + quad * 4;
    USH* ybbase = yb + ((size_t)b * 64 + quad * 16 + vvch) * NN + ybase * HH;

#define CONV_EPILOGUE(ACC, RVAL)                                                            \
    {                                                                                       \
        _Pragma("unroll")                                                                   \
        for (int xi = 0; xi < 6; ++xi) {                                                    \
            int x = xh * 96 + wx * 48 + (RVAL) + 8 * xi;                                    \
            float l0 = ACC[xi][0] + lcr0, l1 = ACC[xi][1] + lcr1;                           \
            float l2 = ACC[xi][2] + lcr2, l3 = ACC[xi][3] + lcr3;                           \
            const USH* qp = qbase + (size_t)x * 64;                                         \
            float s0, s1, s2, s3;                                                           \
            {                                                                               \
                ushort4 q4 = *(const ushort4*)(qp);                                         \
                s0 = bf2f(q4.x) * l0 + bf2f(q4.y) * l1 + bf2f(q4.z) * l2 + bf2f(q4.w) * l3; \
            }                                                                               \
            {                                                                               \
                ushort4 q4 = *(const ushort4*)(qp + 16);                                    \
                s1 = bf2f(q4.x) * l0 + bf2f(q4.y) * l1 + bf2f(q4.z) * l2 + bf2f(q4.w) * l3; \
            }                                                                               \
            {                                                                               \
                ushort4 q4 = *(const ushort4*)(qp + 32);                                    \
                s2 = bf2f(q4.x) * l0 + bf2f(q4.y) * l1 + bf2f(q4.z) * l2 + bf2f(q4.w) * l3; \
            }                                                                               \
            {                                                                               \
                ushort4 q4 = *(const ushort4*)(qp + 48);                                    \
                s3 = bf2f(q4.x) * l0 + bf2f(q4.y) * l1 + bf2f(q4.z) * l2 + bf2f(q4.w) * l3; \
            }                                                                               \
            s0 += __shfl_xor(s0, 16); s0 += __shfl_xor(s0, 32);                             \
            s1 += __shfl_xor(s1, 16); s1 += __shfl_xor(s1, 32);                             \
            s2 += __shfl_xor(s2, 16); s2 += __shfl_xor(s2, 32);                             \
            s3 += __shfl_xor(s3, 16); s3 += __shfl_xor(s3, 32);                             \
            float sel = (quad == 0) ? s0 : (quad == 1) ? s1 : (quad == 2) ? s2 : s3;        \
            ybbase[x] = f2bf(sel);                                                          \
        }                                                                                   \
    }

    for (int rp = 0; rp < 4; ++rp) {
        f32x4 acc0[6] = {};
        f32x4 acc1[6] = {};
        for (int u = 0; u < 4; ++u) {
            const bf16x8* ap0 = apre + ((size_t)((2 * rp) * 4 + u) * 23) * 64 + lane;
            const bf16x8* ap1 = ap0 + 4 * 23 * 64;       // r = 2rp+1
            const USH* su = sbase + u * (54 * 136);
            #pragma unroll
            for (int dy = 0; dy < 23; ++dy) {
                bf16x8 a0 = ap0[dy * 64];
                bf16x8 a1 = ap1[dy * 64];
                const USH* srow = su + dy * 136;
                #pragma unroll
                for (int xi = 0; xi < 6; ++xi) {
                    bf16x8 bfr = *(const bf16x8*)(srow + 8 * xi);
                    acc0[xi] = MFMA16(a0, bfr, acc0[xi]);
                    acc1[xi] = MFMA16(a1, bfr, acc1[xi]);
                }
            }
        }
        CONV_EPILOGUE(acc0, rp * 2)
        CONV_EPILOGUE(acc1, rp * 2 + 1)
    }
#undef CONV_EPILOGUE
}

// ---------------------------------------------------------------- GroupNorm
__global__ void gn_passA_k(const USH* __restrict__ yb, float* __restrict__ part) {
    int bid = blockIdx.x;                  // (b*8+g)*18 + cz
    int cz = bid % 18; int bg = bid / 18;
    int tid = threadIdx.x;
    const USH* base = yb + (size_t)bg * 8 * NN + cz * 2048;
    float s = 0.f, sq = 0.f;
    for (int c = 0; c < 8; ++c) {
        const USH* p = base + (size_t)c * NN;
        for (int i = tid * 4; i < 2048; i += 1024) {
            ushort4 t4 = *(const ushort4*)(p + i);
            float f0 = bf2f(t4.x), f1 = bf2f(t4.y), f2 = bf2f(t4.z), f3 = bf2f(t4.w);
            s += f0 + f1 + f2 + f3;
            sq += f0 * f0 + f1 * f1 + f2 * f2 + f3 * f3;
        }
    }
    for (int off = 32; off; off >>= 1) { s += __shfl_down(s, off); sq += __shfl_down(sq, off); }
    __shared__ float rs[4], rq[4];
    int w = tid >> 6, lane = tid & 63;
    if (lane == 0) { rs[w] = s; rq[w] = sq; }
    __syncthreads();
    if (tid == 0) {
        part[bid * 2]     = rs[0] + rs[1] + rs[2] + rs[3];
        part[bid * 2 + 1] = rq[0] + rq[1] + rq[2] + rq[3];
    }
}
__global__ void gn_passB_k(const float* __restrict__ part, float* __restrict__ stats) {
    int t = threadIdx.x;
    if (t < 32) {
        float s = 0.f, q = 0.f;
        for (int c = 0; c < 18; ++c) { s += part[(t * 18 + c) * 2]; q += part[(t * 18 + c) * 2 + 1]; }
        float mean = s / 294912.0f;
        float var = q / 294912.0f - mean * mean;
        stats[t * 2] = mean;
        stats[t * 2 + 1] = rsqrtf(fmaxf(var, 0.0f) + 1e-5f);
    }
}
// normalize + affine + transpose to XT[b][n][c]  (gamma/beta fp32)
__global__ void gn_passC_k(const USH* __restrict__ yb, const float* __restrict__ stats,
                           const float* __restrict__ gg, const float* __restrict__ gb,
                           USH* __restrict__ out) {
    __shared__ float tf[64][65];
    __shared__ float sc[64], sb[64];
    int bid = blockIdx.x; int b = bid / 576; int nt = bid - b * 576; int n0 = nt * 64;
    int tid = threadIdx.x;
    if (tid < 64) {
        int g = tid >> 3;
        float mean = stats[(b * 8 + g) * 2], rstd = stats[(b * 8 + g) * 2 + 1];
        float ga = gg[tid];
        sc[tid] = rstd * ga;
        sb[tid] = gb[tid] - mean * rstd * ga;
    }
    __syncthreads();
    for (int p = 0; p < 16; ++p) {
        int idx = p * 256 + tid; int c = idx >> 6, nn = idx & 63;
        tf[nn][c] = bf2f(yb[((size_t)b * 64 + c) * NN + n0 + nn]) * sc[c] + sb[c];
    }
    __syncthreads();
    for (int p = 0; p < 16; ++p) {
        int idx = p * 256 + tid; int nn = idx >> 6, c = idx & 63;
        out[((size_t)b * NN + n0 + nn) * 64 + c] = f2bf(tf[nn][c]);
    }
}

// ---------------------------------------------------------------- final conv1x1 + *0.2 + x (fp32 out)
__global__ __launch_bounds__(256) void final_gemm_k(
    const USH* __restrict__ XT, const bf16x8* __restrict__ apre,
    const float* __restrict__ cb, const float* __restrict__ xin, float* __restrict__ out) {
    const int tid = threadIdx.x, lane = tid & 63, wv = tid >> 6;
    const int gw = blockIdx.x * 4 + wv;
    const int nl = lane & 15, quad = lane >> 4;
    bf16x8 afr[8];
    #pragma unroll
    for (int i = 0; i < 8; ++i) afr[i] = apre[i * 64 + lane];
    for (int t = 0; t < 16; ++t) {
        int tile = gw * 16 + t;
        int b = tile / 2304, nt = tile - b * 2304;
        int n = nt * 16 + nl;
        const USH* xrow = XT + ((size_t)b * NN + n) * 64 + quad * 8;
        bf16x8 b0 = *(const bf16x8*)(xrow);
        bf16x8 b1 = *(const bf16x8*)(xrow + 32);
        #pragma unroll
        for (int mt = 0; mt < 4; ++mt) {
            f32x4 acc = {0.f, 0.f, 0.f, 0.f};
            acc = MFMA16(afr[mt * 2 + 0], b0, acc);
            acc = MFMA16(afr[mt * 2 + 1], b1, acc);
            int o0 = mt * 16 + quad * 4;
            float4 cb4 = *(const float4*)(cb + o0);
            float cbv[4] = { cb4.x, cb4.y, cb4.z, cb4.w };
            #pragma unroll
            for (int rg = 0; rg < 4; ++rg) {
                int o = o0 + rg;
                float xv = xin[((size_t)b * 64 + o) * NN + n];
                out[((size_t)b * 64 + o) * NN + n] = (acc[rg] + cbv[rg]) * 0.2f + xv;
            }
        }
    }
}

// ================================================================ host
extern "C" void kernel_launch(void* const* d_in, const int* in_sizes, int n_in,
                              void* d_out, int out_size, void* d_ws, size_t ws_size,
                              hipStream_t stream) {
    (void)in_sizes; (void)n_in; (void)out_size; (void)ws_size;
    const float* x = (const float*)d_in[0];
    char* ws = (char*)d_ws;

    // Workspace layout: 4 big bf16 planes + small tail = ~73.3 MiB total.
    // ybuf aliases kbuf (kbuf is dead after lamc_stage1).
    const size_t SZP = (size_t)NTOT * 64 * 2;          // 18,874,368 B
    USH*   XT    = (USH*)(ws);
    USH*   qT    = (USH*)(ws + SZP);
    USH*   kbuf  = (USH*)(ws + 2 * SZP);
    USH*   ybuf  = kbuf;                               // alias
    USH*   vbuf  = (USH*)(ws + 3 * SZP);
    char*  tail  = ws + 4 * SZP;
    USH*   apc   = (USH*)(tail);            tail += 753664;   // conv A-frags
    USH*   apq   = (USH*)(tail);            tail += 24576;    // qkv A-frags
    float* biasq = (float*)(tail);          tail += 768;
    USH*   apf   = (USH*)(tail);            tail += 8192;     // final A-frags
    float* lcp   = (float*)(tail);          tail += 589824;   // lam_c partials
    float* lcf   = (float*)(tail);          tail += 4096;     // lam_c + pb, [b][vv][kk]
    float* gnp   = (float*)(tail);          tail += 4608;     // GN partials
    float* gns   = (float*)(tail);                            // GN mean/rstd (256 B)

    transpose64_k<<<2304, 256, 0, stream>>>(x, XT);

    for (int L = 0; L < 3; ++L) {
        int base = 1 + L * 9;
        const float* wq = (const float*)d_in[base + 0];
        const float* wk = (const float*)d_in[base + 1];
        const float* wv = (const float*)d_in[base + 2];
        const float* qg = (const float*)d_in[base + 3];
        const float* qb = (const float*)d_in[base + 4];
        const float* vg = (const float*)d_in[base + 5];
        const float* vb = (const float*)d_in[base + 6];
        const float* pw = (const float*)d_in[base + 7];
        const float* pb = (const float*)d_in[base + 8];

        prep_qkv_k<<<6, 256, 0, stream>>>(wq, wk, wv, qg, qb, vg, vb, apq, biasq);
        prep_conv_k<<<184, 256, 0, stream>>>(pw, apc);
        qkv_gemm_k<<<144, 256, 0, stream>>>(XT, (const bf16x8*)apq, biasq, qT, kbuf, vbuf);
        softmax_k<<<256, 1024, 0, stream>>>(kbuf);
        lamc_stage1_k<<<576, 256, 0, stream>>>(kbuf, vbuf, lcp);
        lamc_stage2_k<<<4, 256, 0, stream>>>(lcp, pb, lcf);
        dim3 cg(2, 6, 64);
        conv_pos_fused_k<<<cg, 256, 0, stream>>>(vbuf, (const bf16x8*)apc, qT, lcf, ybuf);
        gn_passA_k<<<576, 256, 0, stream>>>(ybuf, gnp);
        gn_passB_k<<<1, 256, 0, stream>>>(gnp, gns);
        const float* gg = (const float*)d_in[(L == 2) ? 30 : 28];
        const float* gb = (const float*)d_in[(L == 2) ? 31 : 29];
        gn_passC_k<<<2304, 256, 0, stream>>>(ybuf, gns, gg, gb, XT);
    }

    prep_fin_k<<<2, 256, 0, stream>>>((const float*)d_in[32], apf);
    final_gemm_k<<<144, 256, 0, stream>>>(XT, (const bf16x8*)apf,
                                          (const float*)d_in[33], x, (float*)d_out);
}

// Round 7
// 1218.518 us; speedup vs baseline: 3.9288x; 1.3121x over previous
//
#include <hip/hip_runtime.h>

typedef unsigned short USH;
typedef __attribute__((ext_vector_type(8))) short bf16x8;   // 8 bf16 = 4 VGPR
typedef __attribute__((ext_vector_type(4))) float f32x4;

#define MFMA16(a,b,c) __builtin_amdgcn_mfma_f32_16x16x32_bf16((a),(b),(c),0,0,0)

#define BB 4
#define HH 192
#define NN 36864            // 192*192
#define NTOT 147456         // 4*NN
#define CSTR 120            // conv LDS row stride (USH); 118 needed, 120 keeps 16B align, 51.9KB -> 3 blocks/CU

__device__ __forceinline__ float bf2f(USH h) {
    union { unsigned int u; float f; } v; v.u = ((unsigned int)h) << 16; return v.f;
}
__device__ __forceinline__ USH f2bf(float f) {
    union { float f; unsigned int u; } v; v.f = f;
    unsigned int u = v.u;
    return (USH)((u + 0x7FFFu + ((u >> 16) & 1u)) >> 16);
}

// ---------------------------------------------------------------- transpose x: fp32 [b][c][n] -> bf16 [b][n][c]
__global__ void transpose64_k(const float* __restrict__ in, USH* __restrict__ out) {
    __shared__ float tf[64][65];
    int bid = blockIdx.x; int b = bid / 576; int nt = bid - b * 576; int n0 = nt * 64;
    int tid = threadIdx.x;
    for (int p = 0; p < 16; ++p) {
        int idx = p * 256 + tid; int c = idx >> 6, nn = idx & 63;
        tf[nn][c] = in[((size_t)b * 64 + c) * NN + n0 + nn];
    }
    __syncthreads();
    for (int p = 0; p < 16; ++p) {
        int idx = p * 256 + tid; int nn = idx >> 6, c = idx & 63;
        out[((size_t)b * NN + n0 + nn) * 64 + c] = f2bf(tf[nn][c]);
    }
}

// ---------------------------------------------------------------- ALL weight prep in ONE dispatch
// blocks 0..551: conv A-frags (184 blocks x 3 layers); 552..569: qkv frags+bias (6 x 3); 570..571: final frags
struct PrepArgs {
    const float* wq[3]; const float* wk[3]; const float* wv[3];
    const float* qg[3]; const float* qb[3]; const float* vg[3]; const float* vb[3];
    const float* pw[3]; const float* cw;
};
__global__ void prep_all_k(PrepArgs pa, USH* __restrict__ apc, USH* __restrict__ apq,
                           float* __restrict__ biasq, USH* __restrict__ apf) {
    int bid = blockIdx.x, tid = threadIdx.x;
    if (bid < 552) {
        // conv A-frags: chunk cg=(r*4+u)*23+dy ; slot k=(lane>>4)*8+j -> dx=k-r ; kk=lane&15
        int L = bid / 184, cb = bid - L * 184;
        int t = cb * 256 + tid;
        if (t < 736 * 64) {
            const float* pw = pa.pw[L];
            USH* ap = apc + (size_t)L * 376832;       // 736*64*8 USH per layer
            int lane = t & 63, cg = t >> 6;
            int dy = cg % 23; int ru = cg / 23; int u = ru & 3; int r = ru >> 2;
            int kk = lane & 15, q8 = (lane >> 4) * 8;
            for (int j = 0; j < 8; ++j) {
                int k = q8 + j, dx = k - r;
                USH w = 0;
                if (dx >= 0 && dx < 23) w = f2bf(pw[((kk * 4 + u) * 23 + dy) * 23 + dx]);
                ap[t * 8 + j] = w;
            }
        }
    } else if (bid < 570) {
        // qkv A-frags: o = mt*16+(lane&15), c = kc*32+(lane>>4)*8+j
        int idx = bid - 552; int L = idx / 6; int qblk = idx - L * 6;
        int t = qblk * 256 + tid;
        USH* apl = apq + (size_t)L * 12288;
        float* bl = biasq + L * 192;
        if (t < 1536) {
            int lane = t & 63, chunk = t >> 6;
            int mt = chunk >> 1, kc = chunk & 1;
            int o = mt * 16 + (lane & 15);
            int c0 = kc * 32 + (lane >> 4) * 8;
            float scale; const float* wrow;
            if (o < 64)       { scale = pa.qg[L][o]       * rsqrtf(1.0f + 1e-5f); wrow = pa.wq[L] + o * 64; }
            else if (o < 128) { scale = 1.0f;                                     wrow = pa.wk[L] + (o - 64) * 64; }
            else              { scale = pa.vg[L][o - 128] * rsqrtf(1.0f + 1e-5f); wrow = pa.wv[L] + (o - 128) * 64; }
            for (int j = 0; j < 8; ++j) apl[t * 8 + j] = f2bf(wrow[c0 + j] * scale);
        }
        if (t < 192) {
            float bvv;
            if (t < 64) bvv = pa.qb[L][t]; else if (t < 128) bvv = 0.0f; else bvv = pa.vb[L][t - 128];
            bl[t] = bvv;
        }
    } else {
        int t = (bid - 570) * 256 + tid;
        if (t < 512) {
            int lane = t & 63, chunk = t >> 6;
            int mt = chunk >> 1, kc = chunk & 1;
            int o = mt * 16 + (lane & 15);
            int c0 = kc * 32 + (lane >> 4) * 8;
            for (int j = 0; j < 8; ++j) apf[t * 8 + j] = f2bf(pa.cw[o * 64 + c0 + j]);
        }
    }
}

// ---------------------------------------------------------------- QKV GEMM (MFMA, B from global XT)
__global__ __launch_bounds__(256) void qkv_gemm_k(
    const USH* __restrict__ XT, const bf16x8* __restrict__ apre, const float* __restrict__ bias,
    USH* __restrict__ qT, USH* __restrict__ kbuf, USH* __restrict__ vbuf) {
    const int tid = threadIdx.x, lane = tid & 63, wv = tid >> 6;
    const int gw = blockIdx.x * 4 + wv;
    const int nl = lane & 15, quad = lane >> 4;
    bf16x8 afr[24];
    #pragma unroll
    for (int i = 0; i < 24; ++i) afr[i] = apre[i * 64 + lane];
    for (int t = 0; t < 16; ++t) {
        int tile = gw * 16 + t;
        int b = tile / 2304, nt = tile - b * 2304;
        int n = nt * 16 + nl;
        const USH* xrow = XT + ((size_t)b * NN + n) * 64 + quad * 8;
        bf16x8 b0 = *(const bf16x8*)(xrow);
        bf16x8 b1 = *(const bf16x8*)(xrow + 32);
        #pragma unroll
        for (int mt = 0; mt < 12; ++mt) {
            f32x4 acc = {0.f, 0.f, 0.f, 0.f};
            acc = MFMA16(afr[mt * 2 + 0], b0, acc);
            acc = MFMA16(afr[mt * 2 + 1], b1, acc);
            int o0 = mt * 16 + quad * 4;
            float4 bs = *(const float4*)(bias + o0);
            float v0 = acc[0] + bs.x, v1 = acc[1] + bs.y, v2 = acc[2] + bs.z, v3 = acc[3] + bs.w;
            if (mt < 4) {                       // q -> qT[b][n][o] (o = h*16+kk)
                ushort4 pk; pk.x = f2bf(v0); pk.y = f2bf(v1); pk.z = f2bf(v2); pk.w = f2bf(v3);
                *(ushort4*)(qT + ((size_t)b * NN + n) * 64 + o0) = pk;
            } else if (mt < 8) {                // k raw -> kbuf[b][u*16+kk][n]
                int ko = o0 - 64;
                kbuf[((size_t)b * 64 + ko    ) * NN + n] = f2bf(v0);
                kbuf[((size_t)b * 64 + ko + 1) * NN + n] = f2bf(v1);
                kbuf[((size_t)b * 64 + ko + 2) * NN + n] = f2bf(v2);
                kbuf[((size_t)b * 64 + ko + 3) * NN + n] = f2bf(v3);
            } else {                            // v -> vbuf[(b*16+vv)*4+u][n]
                int u = mt - 8, vv0 = quad * 4;
                vbuf[(((size_t)b * 16 + vv0    ) * 4 + u) * NN + n] = f2bf(v0);
                vbuf[(((size_t)b * 16 + vv0 + 1) * 4 + u) * NN + n] = f2bf(v1);
                vbuf[(((size_t)b * 16 + vv0 + 2) * 4 + u) * NN + n] = f2bf(v2);
                vbuf[(((size_t)b * 16 + vv0 + 3) * 4 + u) * NN + n] = f2bf(v3);
            }
        }
    }
}

// ---------------------------------------------------------------- softmax over n, in-place, 1 block/row
__global__ void softmax_k(USH* __restrict__ kbuf) {
    USH* p = kbuf + (size_t)blockIdx.x * NN;
    __shared__ float red[64];
    int tid = threadIdx.x, lane = tid & 63, w = tid >> 6;
    float m = -1e30f;
    for (int i = tid; i < NN; i += 1024) m = fmaxf(m, bf2f(p[i]));
    for (int off = 32; off; off >>= 1) m = fmaxf(m, __shfl_down(m, off));
    if (lane == 0) red[w] = m;
    __syncthreads();
    if (tid == 0) { float mm = red[0]; for (int i = 1; i < 16; ++i) mm = fmaxf(mm, red[i]); red[16] = mm; }
    __syncthreads();
    float M = red[16];
    float s = 0.f;
    for (int i = tid; i < NN; i += 1024) s += __expf(bf2f(p[i]) - M);
    for (int off = 32; off; off >>= 1) s += __shfl_down(s, off);
    if (lane == 0) red[32 + w] = s;
    __syncthreads();
    if (tid == 0) { float ss = 0.f; for (int i = 0; i < 16; ++i) ss += red[32 + i]; red[17] = 1.0f / ss; }
    __syncthreads();
    float inv = red[17];
    for (int i = tid; i < NN; i += 1024) p[i] = f2bf(__expf(bf2f(p[i]) - M) * inv);
}

// ---------------------------------------------------------------- lam_c split-K
__global__ void lamc_stage1_k(const USH* __restrict__ kbuf, const USH* __restrict__ vbuf,
                              float* __restrict__ part) {
    int bid = blockIdx.x;                  // (cidx 0..35)*16 + b*4 + u
    int cidx = bid / 16; int rem = bid - cidx * 16; int b = rem >> 2; int u = rem & 3;
    int tid = threadIdx.x; int vv = tid >> 4; int kk = tid & 15;
    const USH* kp = kbuf + ((size_t)b * 64 + u * 16 + kk) * NN + cidx * 1024;
    const USH* vp = vbuf + (((size_t)b * 16 + vv) * 4 + u) * NN + cidx * 1024;
    float acc = 0.f;
    for (int i = 0; i < 1024; i += 4) {
        ushort4 k4 = *(const ushort4*)(kp + i);
        ushort4 v4 = *(const ushort4*)(vp + i);
        acc += bf2f(k4.x) * bf2f(v4.x) + bf2f(k4.y) * bf2f(v4.y)
             + bf2f(k4.z) * bf2f(v4.z) + bf2f(k4.w) * bf2f(v4.w);
    }
    part[((size_t)(cidx * 4 + b) * 4 + u) * 256 + tid] = acc;
}
__global__ void lamc_stage2_k(const float* __restrict__ part, const float* __restrict__ pb,
                              float* __restrict__ lamcf) {
    int b = blockIdx.x, tid = threadIdx.x;   // tid = vv*16+kk
    float acc = 0.f;
    for (int c = 0; c < 36; ++c)
        for (int u = 0; u < 4; ++u)
            acc += part[((size_t)(c * 4 + b) * 4 + u) * 256 + tid];
    lamcf[b * 256 + tid] = acc + pb[tid & 15];   // fold conv bias pb[kk]
}

// ---------------------------------------------------------------- position conv 23x23 (MFMA implicit GEMM)
// + FUSED y-epilogue. 3-way r-blocking in the R6-proven clean shape (dy fully
// unrolled, inline A-loads, NAMED acc arrays; ~115 live VGPRs stays under the
// compiler's 128-reg spill wall that killed the 4-way attempt).
// Passes: r={0,1,2},{3,4,5},{6,7} -> 1656 LDS reads/wave (vs R6 2208, R3 4416).
// LDS row stride 120 USH -> 51.9KB -> 3 blocks/CU resident (was 2 at 58.9KB).
// D-frag: row kk = quad*4+reg, col y = lane&15. shfl_xor(16,32) completes kk-sum.
__global__ __launch_bounds__(256, 2) void conv_pos_fused_k(
    const USH* __restrict__ vbuf, const bf16x8* __restrict__ apre,
    const USH* __restrict__ qT, const float* __restrict__ lamcf,
    USH* __restrict__ yb) {
    __shared__ __align__(16) USH in_s[4 * 54 * CSTR];     // 51,840 B
    __shared__ float lc_s[16];
    const int xh = blockIdx.x, yt = blockIdx.y, img = blockIdx.z;
    const int b = img >> 4, vvch = img & 15;
    const int tid = threadIdx.x;
    if (tid < 16) lc_s[tid] = lamcf[b * 256 + vvch * 16 + tid];
    {
        const USH* vb = vbuf + (size_t)img * 4 * NN;
        const int y0 = yt * 32 - 11, x0 = xh * 96 - 11;
        for (int idx = tid; idx < 4 * 54 * CSTR; idx += 256) {
            int u = idx / (54 * CSTR);
            int rem = idx - u * (54 * CSTR);
            int rr = rem / CSTR;
            int cc = rem - rr * CSTR;
            int gy = y0 + rr, gx = x0 + cc;
            USH val = 0;
            if (gy >= 0 && gy < HH && gx >= 0 && gx < HH) val = vb[u * NN + gy * HH + gx];
            in_s[idx] = val;
        }
    }
    __syncthreads();

    const int lane = tid & 63, wv = tid >> 6;
    const int wy = wv >> 1, wx = wv & 1;
    const int nl = lane & 15, quad = lane >> 4;
    const USH* sbase = in_s + (wy * 16 + nl) * CSTR + wx * 48 + quad * 8;
    const int ybase = yt * 32 + wy * 16 + nl;
    float lcr0 = lc_s[quad * 4], lcr1 = lc_s[quad * 4 + 1],
          lcr2 = lc_s[quad * 4 + 2], lcr3 = lc_s[quad * 4 + 3];
    const USH* qbase = qT + ((size_t)b * NN + ybase * HH) * 64 + quad * 4;
    USH* ybbase = yb + ((size_t)b * 64 + quad * 16 + vvch) * NN + ybase * HH;

#define CONV_EPILOGUE(ACC, RVAL)                                                            \
    {                                                                                       \
        _Pragma("unroll")                                                                   \
        for (int xi = 0; xi < 6; ++xi) {                                                    \
            int x = xh * 96 + wx * 48 + (RVAL) + 8 * xi;                                    \
            float l0 = ACC[xi][0] + lcr0, l1 = ACC[xi][1] + lcr1;                           \
            float l2 = ACC[xi][2] + lcr2, l3 = ACC[xi][3] + lcr3;                           \
            const USH* qp = qbase + (size_t)x * 64;                                         \
            float s0, s1, s2, s3;                                                           \
            {                                                                               \
                ushort4 q4 = *(const ushort4*)(qp);                                         \
                s0 = bf2f(q4.x) * l0 + bf2f(q4.y) * l1 + bf2f(q4.z) * l2 + bf2f(q4.w) * l3; \
            }                                                                               \
            {                                                                               \
                ushort4 q4 = *(const ushort4*)(qp + 16);                                    \
                s1 = bf2f(q4.x) * l0 + bf2f(q4.y) * l1 + bf2f(q4.z) * l2 + bf2f(q4.w) * l3; \
            }                                                                               \
            {                                                                               \
                ushort4 q4 = *(const ushort4*)(qp + 32);                                    \
                s2 = bf2f(q4.x) * l0 + bf2f(q4.y) * l1 + bf2f(q4.z) * l2 + bf2f(q4.w) * l3; \
            }                                                                               \
            {                                                                               \
                ushort4 q4 = *(const ushort4*)(qp + 48);                                    \
                s3 = bf2f(q4.x) * l0 + bf2f(q4.y) * l1 + bf2f(q4.z) * l2 + bf2f(q4.w) * l3; \
            }                                                                               \
            s0 += __shfl_xor(s0, 16); s0 += __shfl_xor(s0, 32);                             \
            s1 += __shfl_xor(s1, 16); s1 += __shfl_xor(s1, 32);                             \
            s2 += __shfl_xor(s2, 16); s2 += __shfl_xor(s2, 32);                             \
            s3 += __shfl_xor(s3, 16); s3 += __shfl_xor(s3, 32);                             \
            float sel = (quad == 0) ? s0 : (quad == 1) ? s1 : (quad == 2) ? s2 : s3;        \
            ybbase[x] = f2bf(sel);                                                          \
        }                                                                                   \
    }

#define CONV_PASS3(R0)                                                                      \
    {                                                                                       \
        f32x4 acc0[6] = {}; f32x4 acc1[6] = {}; f32x4 acc2[6] = {};                         \
        for (int u = 0; u < 4; ++u) {                                                       \
            const bf16x8* ap0 = apre + ((size_t)((R0) * 4 + u) * 23) * 64 + lane;           \
            const bf16x8* ap1 = ap0 + 4 * 23 * 64;                                          \
            const bf16x8* ap2 = ap0 + 2 * 4 * 23 * 64;                                      \
            const USH* su = sbase + u * (54 * CSTR);                                        \
            _Pragma("unroll")                                                               \
            for (int dy = 0; dy < 23; ++dy) {                                               \
                bf16x8 a0 = ap0[dy * 64], a1 = ap1[dy * 64], a2 = ap2[dy * 64];             \
                const USH* srow = su + dy * CSTR;                                           \
                _Pragma("unroll")                                                           \
                for (int xi = 0; xi < 6; ++xi) {                                            \
                    bf16x8 bfr = *(const bf16x8*)(srow + 8 * xi);                           \
                    acc0[xi] = MFMA16(a0, bfr, acc0[xi]);                                   \
                    acc1[xi] = MFMA16(a1, bfr, acc1[xi]);                                   \
                    acc2[xi] = MFMA16(a2, bfr, acc2[xi]);                                   \
                }                                                                           \
            }                                                                               \
        }                                                                                   \
        CONV_EPILOGUE(acc0, (R0))                                                           \
        CONV_EPILOGUE(acc1, (R0) + 1)                                                       \
        CONV_EPILOGUE(acc2, (R0) + 2)                                                       \
    }

    CONV_PASS3(0)
    CONV_PASS3(3)
    {   // last pass: r = 6,7
        f32x4 acc0[6] = {}; f32x4 acc1[6] = {};
        for (int u = 0; u < 4; ++u) {
            const bf16x8* ap0 = apre + ((size_t)(6 * 4 + u) * 23) * 64 + lane;
            const bf16x8* ap1 = ap0 + 4 * 23 * 64;
            const USH* su = sbase + u * (54 * CSTR);
            #pragma unroll
            for (int dy = 0; dy < 23; ++dy) {
                bf16x8 a0 = ap0[dy * 64], a1 = ap1[dy * 64];
                const USH* srow = su + dy * CSTR;
                #pragma unroll
                for (int xi = 0; xi < 6; ++xi) {
                    bf16x8 bfr = *(const bf16x8*)(srow + 8 * xi);
                    acc0[xi] = MFMA16(a0, bfr, acc0[xi]);
                    acc1[xi] = MFMA16(a1, bfr, acc1[xi]);
                }
            }
        }
        CONV_EPILOGUE(acc0, 6)
        CONV_EPILOGUE(acc1, 7)
    }
#undef CONV_PASS3
#undef CONV_EPILOGUE
}

// ---------------------------------------------------------------- GroupNorm
__global__ void gn_passA_k(const USH* __restrict__ yb, float* __restrict__ part) {
    int bid = blockIdx.x;                  // (b*8+g)*18 + cz
    int cz = bid % 18; int bg = bid / 18;
    int tid = threadIdx.x;
    const USH* base = yb + (size_t)bg * 8 * NN + cz * 2048;
    float s = 0.f, sq = 0.f;
    for (int c = 0; c < 8; ++c) {
        const USH* p = base + (size_t)c * NN;
        for (int i = tid * 4; i < 2048; i += 1024) {
            ushort4 t4 = *(const ushort4*)(p + i);
            float f0 = bf2f(t4.x), f1 = bf2f(t4.y), f2 = bf2f(t4.z), f3 = bf2f(t4.w);
            s += f0 + f1 + f2 + f3;
            sq += f0 * f0 + f1 * f1 + f2 * f2 + f3 * f3;
        }
    }
    for (int off = 32; off; off >>= 1) { s += __shfl_down(s, off); sq += __shfl_down(sq, off); }
    __shared__ float rs[4], rq[4];
    int w = tid >> 6, lane = tid & 63;
    if (lane == 0) { rs[w] = s; rq[w] = sq; }
    __syncthreads();
    if (tid == 0) {
        part[bid * 2]     = rs[0] + rs[1] + rs[2] + rs[3];
        part[bid * 2 + 1] = rq[0] + rq[1] + rq[2] + rq[3];
    }
}
__global__ void gn_passB_k(const float* __restrict__ part, float* __restrict__ stats) {
    int t = threadIdx.x;
    if (t < 32) {
        float s = 0.f, q = 0.f;
        for (int c = 0; c < 18; ++c) { s += part[(t * 18 + c) * 2]; q += part[(t * 18 + c) * 2 + 1]; }
        float mean = s / 294912.0f;
        float var = q / 294912.0f - mean * mean;
        stats[t * 2] = mean;
        stats[t * 2 + 1] = rsqrtf(fmaxf(var, 0.0f) + 1e-5f);
    }
}
// normalize + affine + transpose to XT[b][n][c]  (gamma/beta fp32)
__global__ void gn_passC_k(const USH* __restrict__ yb, const float* __restrict__ stats,
                           const float* __restrict__ gg, const float* __restrict__ gb,
                           USH* __restrict__ out) {
    __shared__ float tf[64][65];
    __shared__ float sc[64], sb[64];
    int bid = blockIdx.x; int b = bid / 576; int nt = bid - b * 576; int n0 = nt * 64;
    int tid = threadIdx.x;
    if (tid < 64) {
        int g = tid >> 3;
        float mean = stats[(b * 8 + g) * 2], rstd = stats[(b * 8 + g) * 2 + 1];
        float ga = gg[tid];
        sc[tid] = rstd * ga;
        sb[tid] = gb[tid] - mean * rstd * ga;
    }
    __syncthreads();
    for (int p = 0; p < 16; ++p) {
        int idx = p * 256 + tid; int c = idx >> 6, nn = idx & 63;
        tf[nn][c] = bf2f(yb[((size_t)b * 64 + c) * NN + n0 + nn]) * sc[c] + sb[c];
    }
    __syncthreads();
    for (int p = 0; p < 16; ++p) {
        int idx = p * 256 + tid; int nn = idx >> 6, c = idx & 63;
        out[((size_t)b * NN + n0 + nn) * 64 + c] = f2bf(tf[nn][c]);
    }
}

// ---------------------------------------------------------------- final conv1x1 + *0.2 + x (fp32 out)
__global__ __launch_bounds__(256) void final_gemm_k(
    const USH* __restrict__ XT, const bf16x8* __restrict__ apre,
    const float* __restrict__ cb, const float* __restrict__ xin, float* __restrict__ out) {
    const int tid = threadIdx.x, lane = tid & 63, wv = tid >> 6;
    const int gw = blockIdx.x * 4 + wv;
    const int nl = lane & 15, quad = lane >> 4;
    bf16x8 afr[8];
    #pragma unroll
    for (int i = 0; i < 8; ++i) afr[i] = apre[i * 64 + lane];
    for (int t = 0; t < 16; ++t) {
        int tile = gw * 16 + t;
        int b = tile / 2304, nt = tile - b * 2304;
        int n = nt * 16 + nl;
        const USH* xrow = XT + ((size_t)b * NN + n) * 64 + quad * 8;
        bf16x8 b0 = *(const bf16x8*)(xrow);
        bf16x8 b1 = *(const bf16x8*)(xrow + 32);
        #pragma unroll
        for (int mt = 0; mt < 4; ++mt) {
            f32x4 acc = {0.f, 0.f, 0.f, 0.f};
            acc = MFMA16(afr[mt * 2 + 0], b0, acc);
            acc = MFMA16(afr[mt * 2 + 1], b1, acc);
            int o0 = mt * 16 + quad * 4;
            float4 cb4 = *(const float4*)(cb + o0);
            float cbv[4] = { cb4.x, cb4.y, cb4.z, cb4.w };
            #pragma unroll
            for (int rg = 0; rg < 4; ++rg) {
                int o = o0 + rg;
                float xv = xin[((size_t)b * 64 + o) * NN + n];
                out[((size_t)b * 64 + o) * NN + n] = (acc[rg] + cbv[rg]) * 0.2f + xv;
            }
        }
    }
}

// ================================================================ host
extern "C" void kernel_launch(void* const* d_in, const int* in_sizes, int n_in,
                              void* d_out, int out_size, void* d_ws, size_t ws_size,
                              hipStream_t stream) {
    (void)in_sizes; (void)n_in; (void)out_size; (void)ws_size;
    const float* x = (const float*)d_in[0];
    char* ws = (char*)d_ws;

    // Workspace: 4 big bf16 planes + tail (all-layer prep tables) ≈ 78 MiB.
    // ybuf aliases kbuf (kbuf dead after lamc_stage1).
    const size_t SZP = (size_t)NTOT * 64 * 2;          // 18,874,368 B
    USH*   XT    = (USH*)(ws);
    USH*   qT    = (USH*)(ws + SZP);
    USH*   kbuf  = (USH*)(ws + 2 * SZP);
    USH*   ybuf  = kbuf;                               // alias
    USH*   vbuf  = (USH*)(ws + 3 * SZP);
    char*  tail  = ws + 4 * SZP;
    USH*   apc   = (USH*)(tail);            tail += 753664 * 3;   // conv A-frags x3 layers
    USH*   apq   = (USH*)(tail);            tail += 24576 * 3;    // qkv A-frags x3
    float* biasq = (float*)(tail);          tail += 768 * 3;
    USH*   apf   = (USH*)(tail);            tail += 8192;         // final A-frags
    float* lcp   = (float*)(tail);          tail += 589824;       // lam_c partials
    float* lcf   = (float*)(tail);          tail += 4096;         // lam_c + pb, [b][vv][kk]
    float* gnp   = (float*)(tail);          tail += 4608;         // GN partials
    float* gns   = (float*)(tail);                                // GN mean/rstd (256 B)

    PrepArgs pa;
    for (int L = 0; L < 3; ++L) {
        int base = 1 + L * 9;
        pa.wq[L] = (const float*)d_in[base + 0];
        pa.wk[L] = (const float*)d_in[base + 1];
        pa.wv[L] = (const float*)d_in[base + 2];
        pa.qg[L] = (const float*)d_in[base + 3];
        pa.qb[L] = (const float*)d_in[base + 4];
        pa.vg[L] = (const float*)d_in[base + 5];
        pa.vb[L] = (const float*)d_in[base + 6];
        pa.pw[L] = (const float*)d_in[base + 7];
    }
    pa.cw = (const float*)d_in[32];

    transpose64_k<<<2304, 256, 0, stream>>>(x, XT);
    prep_all_k<<<572, 256, 0, stream>>>(pa, apc, apq, biasq, apf);

    for (int L = 0; L < 3; ++L) {
        const float* pb = (const float*)d_in[1 + L * 9 + 8];

        qkv_gemm_k<<<144, 256, 0, stream>>>(XT, (const bf16x8*)apq + (size_t)L * 1536,
                                            biasq + L * 192, qT, kbuf, vbuf);
        softmax_k<<<256, 1024, 0, stream>>>(kbuf);
        lamc_stage1_k<<<576, 256, 0, stream>>>(kbuf, vbuf, lcp);
        lamc_stage2_k<<<4, 256, 0, stream>>>(lcp, pb, lcf);
        dim3 cg(2, 6, 64);
        conv_pos_fused_k<<<cg, 256, 0, stream>>>(vbuf, (const bf16x8*)apc + (size_t)L * 47104,
                                                 qT, lcf, ybuf);
        gn_passA_k<<<576, 256, 0, stream>>>(ybuf, gnp);
        gn_passB_k<<<1, 256, 0, stream>>>(gnp, gns);
        const float* gg = (const float*)d_in[(L == 2) ? 30 : 28];
        const float* gb = (const float*)d_in[(L == 2) ? 31 : 29];
        gn_passC_k<<<2304, 256, 0, stream>>>(ybuf, gns, gg, gb, XT);
    }

    final_gemm_k<<<144, 256, 0, stream>>>(XT, (const bf16x8*)apf,
                                          (const float*)d_in[33], x, (float*)d_out);
}